// Round 6
// baseline (226.959 us; speedup 1.0000x reference)
//
#include <hip/hip_runtime.h>
#include <hip/hip_bf16.h>
#include <stdint.h>

#define EPSV 1e-6f
#define N1 4096
#define N2 4096
#define DD 1024
#define NLAYERS 3
#define KKC 10

typedef __bf16 bf16_t;
typedef __bf16 bf16x8 __attribute__((ext_vector_type(8)));
typedef __bf16 bf16x4 __attribute__((ext_vector_type(4)));
typedef float f32x4 __attribute__((ext_vector_type(4)));

// ---------------- workspace layout (bytes) ----------------
#define OFF_CONSTS 0                                   // c[3] at 0..2, pk[3][11] at 8..
#define OFF_A      1024                                // a_tab[3][4096] f32
#define OFF_B      (OFF_A + NLAYERS*N1*4)              // b_tab[3][4096] f32
#define OFF_ZT     (((OFF_B + NLAYERS*N2*4) + 4095) & ~4095)
#define ZT_LSTRIDE ((size_t)N1*DD)
#define IN_LSTRIDE ((size_t)N1*N2)
#define OFF_WT_B   (OFF_ZT + NLAYERS*ZT_LSTRIDE*2)
#define OFF_IN_B   (OFF_WT_B + NLAYERS*ZT_LSTRIDE*2)
#define WS_BATCH   (OFF_IN_B + NLAYERS*IN_LSTRIDE*2)
#define OFF_WT_S   (OFF_ZT + ZT_LSTRIDE*2)
#define OFF_IN_S   (OFF_WT_S + ZT_LSTRIDE*2)
#define WS_FULL    (OFF_IN_S + IN_LSTRIDE*2)
#define WS_MIN     OFF_IN_S

__device__ __forceinline__ float softplus_fast(float x) {
  return fmaxf(x, 0.f) + __logf(1.f + __expf(-fabsf(x)));
}
__device__ __forceinline__ float softplus_ref(float x) {
  return fmaxf(x, 0.f) + log1pf(expf(-fabsf(x)));
}
__device__ __forceinline__ float wredsum(float x) {
  #pragma unroll
  for (int o = 32; o; o >>= 1) x += __shfl_xor(x, o, 64);
  return x;
}
__device__ __forceinline__ float wredmax(float x) {
  #pragma unroll
  for (int o = 32; o; o >>= 1) x = fmaxf(x, __shfl_xor(x, o, 64));
  return x;
}
__device__ __forceinline__ void global_load_lds16(const void* g, void* l) {
  __builtin_amdgcn_global_load_lds(
      (const __attribute__((address_space(1))) uint32_t*)g,
      (__attribute__((address_space(3))) uint32_t*)l, 16, 0, 0);
}

// ---------------- tiny kernels ----------------
__global__ void zero_out(float* out) { if (threadIdx.x == 0) out[0] = 0.f; }

__global__ __launch_bounds__(256) void prep_small(
    const float* __restrict__ lz, const float* __restrict__ lw,
    const float* __restrict__ pks, const float* __restrict__ Lp,
    float* __restrict__ consts, float* __restrict__ a_tab, float* __restrict__ b_tab)
{
  int n = blockIdx.x * blockDim.x + threadIdx.x;
  float Lv = softplus_ref(Lp[0]);
  if (n < N1) {
    float z0 = lz[n*3], z1 = lz[n*3+1], z2 = lz[n*3+2];
    float m = fmaxf(z0, fmaxf(z1, z2));
    float e0 = expf(z0-m), e1 = expf(z1-m), e2 = expf(z2-m);
    float inv = 1.f/(e0+e1+e2);
    a_tab[0*N1+n] = e0*inv*Lv; a_tab[1*N1+n] = e1*inv*Lv; a_tab[2*N1+n] = e2*inv*Lv;
    float w0 = lw[n*3], w1 = lw[n*3+1], w2 = lw[n*3+2];
    m = fmaxf(w0, fmaxf(w1, w2));
    e0 = expf(w0-m); e1 = expf(w1-m); e2 = expf(w2-m);
    inv = 1.f/(e0+e1+e2);
    b_tab[0*N2+n] = e0*inv+EPSV; b_tab[1*N2+n] = e1*inv+EPSV; b_tab[2*N2+n] = e2*inv+EPSV;
  }
  if (n < NLAYERS) {
    float p[KKC+1]; float m = -1e30f;
    for (int k = 0; k <= KKC; ++k) { p[k] = pks[n*(KKC+1)+k]; m = fmaxf(m, p[k]); }
    float s = 0.f;
    for (int k = 0; k <= KKC; ++k) { p[k] = expf(p[k]-m); s += p[k]; }
    float inv = 1.f/s;
    for (int k = 0; k <= KKC; ++k) consts[8 + n*(KKC+1) + k] = p[k]*inv;
    consts[n] = p[0]*inv + EPSV*(1.f - p[0]*inv);  // c = p0 + EPS*(1-p0)
  }
}

// grid (rows, layers): softmax; zmode=1 also applies hierarchical kernel M via pyramid.
__global__ __launch_bounds__(256) void prep_row(
    const float* __restrict__ src, bf16_t* __restrict__ dst, size_t dstLstride,
    const float* __restrict__ consts, int layer0, int zmode)
{
  __shared__ float sm[DD];
  __shared__ float pyr[1024];
  __shared__ float red[4];
  const int t = threadIdx.x;
  const int w = t >> 6, l = t & 63;
  const int n = blockIdx.x;
  const int layer = layer0 + blockIdx.y;
  src += (size_t)layer*N1*DD;
  dst += (size_t)blockIdx.y*dstLstride;
  const float4 u = ((const float4*)(src + (size_t)n*DD))[t];
  float mx = fmaxf(fmaxf(u.x, u.y), fmaxf(u.z, u.w));
  mx = wredmax(mx);
  if (l == 0) red[w] = mx;
  __syncthreads();
  mx = fmaxf(fmaxf(red[0], red[1]), fmaxf(red[2], red[3]));
  float e0 = expf(u.x-mx), e1 = expf(u.y-mx), e2 = expf(u.z-mx), e3 = expf(u.w-mx);
  float s = wredsum(e0+e1+e2+e3);
  __syncthreads();
  if (l == 0) red[w] = s;
  __syncthreads();
  float inv = 1.f/(red[0]+red[1]+red[2]+red[3]);
  e0 *= inv; e1 *= inv; e2 *= inv; e3 *= inv;
  if (!zmode) {
    bf16x4 o; o[0] = (bf16_t)e0; o[1] = (bf16_t)e1; o[2] = (bf16_t)e2; o[3] = (bf16_t)e3;
    *(bf16x4*)(dst + (size_t)n*DD + t*4) = o;
    return;
  }
  float4 f4; f4.x = e0; f4.y = e1; f4.z = e2; f4.w = e3;
  *(float4*)&sm[t*4] = f4;
  __syncthreads();
  for (int idx = t; idx < 512; idx += 256) pyr[idx] = sm[2*idx] + sm[2*idx+1];
  __syncthreads();
  {
    if (t < 256) pyr[512+t]  = pyr[2*t]      + pyr[2*t+1];       __syncthreads();
    if (t < 128) pyr[768+t]  = pyr[512+2*t]  + pyr[512+2*t+1];   __syncthreads();
    if (t <  64) pyr[896+t]  = pyr[768+2*t]  + pyr[768+2*t+1];   __syncthreads();
    if (t <  32) pyr[960+t]  = pyr[896+2*t]  + pyr[896+2*t+1];   __syncthreads();
    if (t <  16) pyr[992+t]  = pyr[960+2*t]  + pyr[960+2*t+1];   __syncthreads();
    if (t <   8) pyr[1008+t] = pyr[992+2*t]  + pyr[992+2*t+1];   __syncthreads();
    if (t <   4) pyr[1016+t] = pyr[1008+2*t] + pyr[1008+2*t+1];  __syncthreads();
    if (t <   2) pyr[1020+t] = pyr[1016+2*t] + pyr[1016+2*t+1];  __syncthreads();
  }
  const float* pk = consts + 8 + layer*(KKC+1);
  const float p1 = pk[1], p2 = pk[2], p3 = pk[3], p4 = pk[4], p5 = pk[5];
  const float p6 = pk[6], p7 = pk[7], p8 = pk[8], p9 = pk[9], p10 = pk[10];
  #pragma unroll
  for (int q = 0; q < 4; ++q) {
    int j = t + q*256;
    float acc = p10*sm[j]
              + p1*pyr[(j>>1)]
              + p2*pyr[512 +(j>>2)]
              + p3*pyr[768 +(j>>3)]
              + p4*pyr[896 +(j>>4)]
              + p5*pyr[960 +(j>>5)]
              + p6*pyr[992 +(j>>6)]
              + p7*pyr[1008+(j>>7)]
              + p8*pyr[1016+(j>>8)]
              + p9*pyr[1020+(j>>9)];
    dst[(size_t)n*DD + j] = (bf16_t)acc;
  }
}

// ---------------- 256x256 8-phase GEMM (T2+T3+T4+T5) + fused epilogue ----------------
// 8 waves (2M x 4N), wave tile 128x64. K-tile BK=64; LDS = 2 bufs x 64KB:
// buf: A[256][64] (32KB, rows = M-panel) then B[256][64] (rows = N-panel), bf16,
// granule-XOR swizzle g^(row&7) on 16B granules (both-sides, verified R5).
// 8 phases per iteration (2 K-tiles). Per phase: one C-quadrant (4m x 2n x K64 = 16 MFMA),
// ds_reads at phase top, ONE half-tile stage (2 gloads/wave), barrier, lgkm0, MFMA, barrier.
// vmcnt(2) ONLY at phases 4 & 8 (counted, never 0 until tail). Prefetch distance 4-7 phases.

__global__ __launch_bounds__(512, 2) void gemm_fused(
    const bf16_t* __restrict__ Az, size_t zls,
    const bf16_t* __restrict__ Bw, size_t wls,
    const float* __restrict__ a_tab, const float* __restrict__ b_tab,
    const float* __restrict__ gamma, const float* __restrict__ delta,
    const float* __restrict__ consts, int layer0,
    bf16_t* __restrict__ inter, size_t ils, float* __restrict__ out)
{
  extern __shared__ char lds[];                // 2 x 64KB
  const int t = threadIdx.x;
  const int w = t >> 6, l = t & 63;
  const int wm = w >> 2, wn = w & 3;           // 2x4 wave grid; wave tile 128x64
  const int fr = l & 15, fq = l >> 4;

  // T1: bijective XCD swizzle (nblk % 8 == 0 in both call sites)
  const int nbx = gridDim.x, nby = gridDim.y;
  int lid = blockIdx.x + nbx*(blockIdx.y + nby*blockIdx.z);
  const int nblk = nbx*nby*gridDim.z;
  const int cpx = nblk >> 3;
  int nid = (lid & 7)*cpx + (lid >> 3);
  const int bz = nid / (nbx*nby);
  const int rem = nid % (nbx*nby);
  const int bi = rem % nbx, bj = rem / nbx;

  const int i0 = bi*256, j0 = bj*256;
  const int layer = layer0 + bz;
  Az += (size_t)bz*zls + (size_t)i0*DD;
  Bw += (size_t)bz*wls + (size_t)j0*DD;
  if (inter) inter += (size_t)bz*ils;

  f32x4 acc[8][4];
  f32x4 zero = {0.f, 0.f, 0.f, 0.f};
  #pragma unroll
  for (int m = 0; m < 8; ++m)
    #pragma unroll
    for (int nn = 0; nn < 4; ++nn) acc[m][nn] = zero;

  // stage-side per-thread constants (2 gloads per STG, each 64 rows x 8 granules)
  const int srow = w*8 + (l >> 3);                  // 0..63
  const int sgs  = (l & 7) ^ (srow & 7);            // T2 pre-swizzled source granule
  const size_t so0 = (size_t)srow*DD + (size_t)sgs*8;
  const size_t so1 = so0 + (size_t)64*DD;
  // read-side base byte offsets (m/nn terms are compile-time immediates)
  const int sx = fr & 7;
  const int aofs0 = wm*16384 + fr*128 + ((0+fq)^sx)*16;          // k=0, +m*2048
  const int aofs1 = wm*16384 + fr*128 + ((4+fq)^sx)*16;          // k=1
  const int bofs0 = 32768 + wn*8192 + fr*128 + ((0+fq)^sx)*16;   // k=0, +nn*2048
  const int bofs1 = 32768 + wn*8192 + fr*128 + ((4+fq)^sx)*16;   // k=1

  bf16x8 ar[8], br[8];

#define STG(matptr, matofs, half, tile) do { \
    const bf16_t* _s = (matptr) + (size_t)(half)*128*DD + (size_t)(tile)*64; \
    char* _d = lds + ((tile)&1)*65536 + (matofs) + (half)*16384 + w*1024; \
    global_load_lds16(_s + so0, _d); \
    global_load_lds16(_s + so1, _d + 8192); \
  } while (0)
#define LDA(bufb, mq) do { \
    const char* _b = lds + (bufb); \
    _Pragma("unroll") for (int i = 0; i < 4; ++i) { \
      ar[i]   = *(const bf16x8*)(_b + aofs0 + ((mq)*4+i)*2048); \
      ar[4+i] = *(const bf16x8*)(_b + aofs1 + ((mq)*4+i)*2048); } \
  } while (0)
#define LDB(bufb, nq) do { \
    const char* _b = lds + (bufb); \
    _Pragma("unroll") for (int j = 0; j < 2; ++j) { \
      br[(nq)*2+j]   = *(const bf16x8*)(_b + bofs0 + ((nq)*2+j)*2048); \
      br[4+(nq)*2+j] = *(const bf16x8*)(_b + bofs1 + ((nq)*2+j)*2048); } \
  } while (0)
#define MM(mq, nq) do { \
    _Pragma("unroll") for (int k = 0; k < 2; ++k) \
    _Pragma("unroll") for (int i = 0; i < 4; ++i) \
    _Pragma("unroll") for (int j = 0; j < 2; ++j) \
      acc[(mq)*4+i][(nq)*2+j] = __builtin_amdgcn_mfma_f32_16x16x32_bf16( \
          ar[k*4+i], br[k*4+(nq)*2+j], acc[(mq)*4+i][(nq)*2+j], 0, 0, 0); \
  } while (0)
#define SYNC_MFMA(mq, nq) do { \
    asm volatile("s_barrier" ::: "memory"); \
    asm volatile("s_waitcnt lgkmcnt(0)" ::: "memory"); \
    __builtin_amdgcn_sched_barrier(0); \
    __builtin_amdgcn_s_setprio(1); \
    MM(mq, nq); \
    __builtin_amdgcn_s_setprio(0); \
  } while (0)
#define CLOSE() asm volatile("s_barrier" ::: "memory")

  // prologue: stage tiles 0 (buf0) and 1 (buf1); retire tile0; barrier
  STG(Az, 0, 0, 0); STG(Az, 0, 1, 0); STG(Bw, 32768, 0, 0); STG(Bw, 32768, 1, 0);
  STG(Az, 0, 0, 1); STG(Az, 0, 1, 1); STG(Bw, 32768, 0, 1); STG(Bw, 32768, 1, 1);
  asm volatile("s_waitcnt vmcnt(8)" ::: "memory");
  asm volatile("s_barrier" ::: "memory");

  for (int it = 0; it < 8; ++it) {
    const int k1 = 2*it + 1;
    const bool sE = (it >= 1);       // ph1-3 stage tile k1 (it0: prologue covered tile1)
    const bool sL = (it <= 6);       // ph4-8 stage tiles k1+1, k1+2

    // ph1: reads buf0 {A m0, B n0} (12); stage A1[k1]->buf1
    LDA(0, 0); LDB(0, 0);
    if (sE) STG(Az, 0, 1, k1);
    asm volatile("s_waitcnt lgkmcnt(8)" ::: "memory");
    SYNC_MFMA(0, 0); CLOSE();
    // ph2: reads {B n1} (4); stage B0[k1]->buf1
    LDB(0, 1);
    if (sE) STG(Bw, 32768, 0, k1);
    SYNC_MFMA(0, 1); CLOSE();
    // ph3: reads {A m1} (8); stage B1[k1]->buf1
    LDA(0, 1);
    if (sE) STG(Bw, 32768, 1, k1);
    SYNC_MFMA(1, 0); CLOSE();
    // ph4: no reads; stage A0[k1+1]->buf0; vmcnt retires tile k1 before ph5 reads
    if (sL) STG(Az, 0, 0, k1+1);
    SYNC_MFMA(1, 1);
    if (it < 7) asm volatile("s_waitcnt vmcnt(2)" ::: "memory");
    else        asm volatile("s_waitcnt vmcnt(0)" ::: "memory");
    CLOSE();

    // ph5: reads buf1 {A m0, B n0}; stage A1[k1+1]->buf0
    LDA(65536, 0); LDB(65536, 0);
    if (sL) STG(Az, 0, 1, k1+1);
    asm volatile("s_waitcnt lgkmcnt(8)" ::: "memory");
    SYNC_MFMA(0, 0); CLOSE();
    // ph6: reads {B n1}; stage B0[k1+1]->buf0
    LDB(65536, 1);
    if (sL) STG(Bw, 32768, 0, k1+1);
    SYNC_MFMA(0, 1); CLOSE();
    // ph7: reads {A m1}; stage B1[k1+1]->buf0
    LDA(65536, 1);
    if (sL) STG(Bw, 32768, 1, k1+1);
    SYNC_MFMA(1, 0); CLOSE();
    // ph8: no reads; stage A0[k1+2]->buf1; vmcnt(2) retires tile k1+1 before next ph1
    if (sL) STG(Az, 0, 0, k1+2);
    SYNC_MFMA(1, 1);
    if (sL) asm volatile("s_waitcnt vmcnt(2)" ::: "memory");
    CLOSE();
  }
#undef STG
#undef LDA
#undef LDB
#undef MM
#undef SYNC_MFMA
#undef CLOSE

  // epilogue: v = a*b*(dot+c) + g + d ; sum softplus(v) off-diagonal; store dot+c
  const float cc = consts[layer];
  const float* at = a_tab + layer*N1;
  const float* bt = b_tab + layer*N2;
  float bv[4], dv[4];
  int colv[4];
  #pragma unroll
  for (int nn = 0; nn < 4; ++nn) {
    colv[nn] = j0 + wn*64 + nn*16 + fr;
    bv[nn] = bt[colv[nn]];
    dv[nn] = delta[colv[nn]*3 + layer];
  }
  float lsum = 0.f;
  #pragma unroll
  for (int m = 0; m < 8; ++m) {
    int rb = i0 + wm*128 + m*16 + fq*4;
    #pragma unroll
    for (int r = 0; r < 4; ++r) {
      int row = rb + r;
      float av = at[row];
      float gv = gamma[row*3 + layer];
      #pragma unroll
      for (int nn = 0; nn < 4; ++nn) {
        float dc = acc[m][nn][r] + cc;
        if (inter) inter[(size_t)row*N2 + colv[nn]] = (bf16_t)dc;
        float v = av*bv[nn]*dc + gv + dv[nn];
        if (row != colv[nn]) lsum += softplus_fast(v);
      }
    }
  }
  lsum = wredsum(lsum);
  __syncthreads();
  if (l == 0) ((float*)lds)[w] = lsum;
  __syncthreads();
  if (t == 0) {
    const float* r = (const float*)lds;
    float s = 0.f;
    #pragma unroll
    for (int i = 0; i < 8; ++i) s += r[i];
    atomicAdd(out, -s);   // ll -= z_pdist1
  }
}

// ---------------- sparse: gather from materialized inter (layer-batched) ----------------
__global__ __launch_bounds__(256) void sparse_gather(
    const int* __restrict__ is_, const int* __restrict__ js_,
    const bf16_t* __restrict__ inter, size_t ils,
    const float* __restrict__ a_tab, const float* __restrict__ b_tab,
    const float* __restrict__ gamma, const float* __restrict__ delta,
    int layer0, int E, float* __restrict__ out)
{
  const int layer = layer0 + blockIdx.y;
  int e = blockIdx.x * blockDim.x + threadIdx.x;
  float v = 0.f;
  if (e < E) {
    int i = is_[(size_t)blockIdx.y*E + e], j = js_[(size_t)blockIdx.y*E + e];
    float dc = (float)inter[(size_t)blockIdx.y*ils + (size_t)i*N2 + j];
    v = a_tab[layer*N1+i] * b_tab[layer*N2+j] * dc + gamma[i*3+layer] + delta[j*3+layer];
  }
  v = wredsum(v);
  __shared__ float red[4];
  int w = threadIdx.x >> 6, l = threadIdx.x & 63;
  if (l == 0) red[w] = v;
  __syncthreads();
  if (threadIdx.x == 0) atomicAdd(out, red[0] + red[1] + red[2] + red[3]);
}

// ---------------- fallback sparse: per-edge dot (ws too small for inter) ----------------
__global__ __launch_bounds__(256) void sparse_dot(
    const int* __restrict__ is_, const int* __restrict__ js_,
    const bf16_t* __restrict__ zt, const bf16_t* __restrict__ wt,
    const float* __restrict__ a_tab, const float* __restrict__ b_tab,
    const float* __restrict__ gamma, const float* __restrict__ delta,
    const float* __restrict__ consts, int layer, float* __restrict__ out)
{
  const int t = threadIdx.x, w = t >> 6, l = t & 63;
  const float cc = consts[layer];
  float accv = 0.f;
  for (int q = 0; q < 8; ++q) {
    int e = (blockIdx.x*4 + w)*8 + q;
    int i = is_[e], j = js_[e];
    const bf16x8* zr = (const bf16x8*)(zt + (size_t)i*DD) + l*2;
    const bf16x8* wr = (const bf16x8*)(wt + (size_t)j*DD) + l*2;
    float dot = 0.f;
    #pragma unroll
    for (int x = 0; x < 2; ++x) {
      bf16x8 a = zr[x], b = wr[x];
      #pragma unroll
      for (int y = 0; y < 8; ++y) dot += (float)a[y] * (float)b[y];
    }
    dot = wredsum(dot);
    if (l == 0)
      accv += a_tab[layer*N1+i]*b_tab[layer*N2+j]*(dot+cc) + gamma[i*3+layer] + delta[j*3+layer];
  }
  __shared__ float red[4];
  if (l == 0) red[w] = accv;
  __syncthreads();
  if (t == 0) atomicAdd(out, red[0] + red[1] + red[2] + red[3]);
}

extern "C" void kernel_launch(void* const* d_in, const int* in_sizes, int n_in,
                              void* d_out, int out_size, void* d_ws, size_t ws_size,
                              hipStream_t stream) {
  const float* us    = (const float*)d_in[0];
  const float* vs    = (const float*)d_in[1];
  const float* gamma = (const float*)d_in[2];
  const float* delta = (const float*)d_in[3];
  const float* lz    = (const float*)d_in[4];
  const float* lw    = (const float*)d_in[5];
  const float* pks   = (const float*)d_in[6];
  const float* Lp    = (const float*)d_in[7];
  const int*   sis   = (const int*)d_in[8];
  const int*   sjs   = (const int*)d_in[9];
  float* out = (float*)d_out;
  char*  ws  = (char*)d_ws;

  float*  consts = (float*)(ws + OFF_CONSTS);
  float*  a_tab  = (float*)(ws + OFF_A);
  float*  b_tab  = (float*)(ws + OFF_B);
  const int E = in_sizes[8] / NLAYERS;
  if (ws_size < WS_MIN) return;
  const size_t LDSB = 131072;

  zero_out<<<1, 64, 0, stream>>>(out);
  prep_small<<<(N1+255)/256, 256, 0, stream>>>(lz, lw, pks, Lp, consts, a_tab, b_tab);

  if (ws_size >= WS_BATCH) {
    bf16_t* zt    = (bf16_t*)(ws + OFF_ZT);
    bf16_t* wt    = (bf16_t*)(ws + OFF_WT_B);
    bf16_t* inter = (bf16_t*)(ws + OFF_IN_B);
    prep_row<<<dim3(N1, NLAYERS), 256, 0, stream>>>(us, zt, ZT_LSTRIDE, consts, 0, 1);
    prep_row<<<dim3(N2, NLAYERS), 256, 0, stream>>>(vs, wt, ZT_LSTRIDE, consts, 0, 0);
    gemm_fused<<<dim3(16,16,NLAYERS), 512, LDSB, stream>>>(
        zt, ZT_LSTRIDE, wt, ZT_LSTRIDE, a_tab, b_tab, gamma, delta,
        consts, 0, inter, IN_LSTRIDE, out);
    sparse_gather<<<dim3((E+255)/256, NLAYERS), 256, 0, stream>>>(
        sis, sjs, inter, IN_LSTRIDE, a_tab, b_tab, gamma, delta, 0, E, out);
  } else {
    bf16_t* zt    = (bf16_t*)(ws + OFF_ZT);
    bf16_t* wt    = (bf16_t*)(ws + OFF_WT_S);
    bf16_t* inter = (bf16_t*)(ws + OFF_IN_S);
    const bool full = ws_size >= WS_FULL;
    for (int lay = 0; lay < NLAYERS; ++lay) {
      prep_row<<<dim3(N1,1), 256, 0, stream>>>(us, zt, 0, consts, lay, 1);
      prep_row<<<dim3(N2,1), 256, 0, stream>>>(vs, wt, 0, consts, lay, 0);
      gemm_fused<<<dim3(16,16,1), 512, LDSB, stream>>>(
          zt, 0, wt, 0, a_tab, b_tab, gamma, delta, consts, lay,
          full ? inter : (bf16_t*)nullptr, 0, out);
      if (full) {
        sparse_gather<<<dim3((E+255)/256,1), 256, 0, stream>>>(
            sis + (size_t)lay*E, sjs + (size_t)lay*E, inter, 0,
            a_tab, b_tab, gamma, delta, lay, E, out);
      } else {
        sparse_dot<<<E/32, 256, 0, stream>>>(
            sis + (size_t)lay*E, sjs + (size_t)lay*E, zt, wt,
            a_tab, b_tab, gamma, delta, consts, lay, out);
      }
    }
  }
}

// Round 7
// 207.507 us; speedup vs baseline: 1.0937x; 1.0937x over previous
//
#include <hip/hip_runtime.h>
#include <hip/hip_bf16.h>
#include <stdint.h>

#define EPSV 1e-6f
#define N1 4096
#define N2 4096
#define DD 1024
#define NLAYERS 3
#define KKC 10

typedef __bf16 bf16_t;
typedef __bf16 bf16x8 __attribute__((ext_vector_type(8)));
typedef float f32x4 __attribute__((ext_vector_type(4)));

// ---------------- workspace layout (bytes) ----------------
#define OFF_CONSTS 0                                   // c[3] at 0..2, pk[3][11] at 8..
#define OFF_A      1024                                // a_tab[3][4096] f32 (softmax(lz)*L)
#define OFF_B      (OFF_A + NLAYERS*N1*4)              // b_tab[3][4096] f32 (softmax(lw)+EPS)
#define OFF_G      (OFF_B + NLAYERS*N2*4)              // g_tab[3][4096] f32 (gamma^T)
#define OFF_D      (OFF_G + NLAYERS*N1*4)              // d_tab[3][4096] f32 (delta^T)
#define OFF_ZT     (((OFF_D + NLAYERS*N2*4) + 4095) & ~4095)
#define ZT_LSTRIDE ((size_t)N1*DD)
#define IN_LSTRIDE ((size_t)N1*N2)
#define OFF_WT_B   (OFF_ZT + NLAYERS*ZT_LSTRIDE*2)
#define OFF_IN_B   (OFF_WT_B + NLAYERS*ZT_LSTRIDE*2)
#define WS_BATCH   (OFF_IN_B + NLAYERS*IN_LSTRIDE*2)
#define OFF_WT_S   (OFF_ZT + ZT_LSTRIDE*2)
#define OFF_IN_S   (OFF_WT_S + ZT_LSTRIDE*2)
#define WS_FULL    (OFF_IN_S + IN_LSTRIDE*2)
#define WS_MIN     OFF_IN_S

__device__ __forceinline__ float softplus_fast(float x) {
  return fmaxf(x, 0.f) + __logf(1.f + __expf(-fabsf(x)));
}
__device__ __forceinline__ float softplus_ref(float x) {
  return fmaxf(x, 0.f) + log1pf(expf(-fabsf(x)));
}
__device__ __forceinline__ float wredsum(float x) {
  #pragma unroll
  for (int o = 32; o; o >>= 1) x += __shfl_xor(x, o, 64);
  return x;
}
__device__ __forceinline__ float wredmax(float x) {
  #pragma unroll
  for (int o = 32; o; o >>= 1) x = fmaxf(x, __shfl_xor(x, o, 64));
  return x;
}
__device__ __forceinline__ void global_load_lds16(const void* g, void* l) {
  __builtin_amdgcn_global_load_lds(
      (const __attribute__((address_space(1))) uint32_t*)g,
      (__attribute__((address_space(3))) uint32_t*)l, 16, 0, 0);
}

// ---------------- prep_small: scalars, a/b/g/d tables, out zero ----------------
__global__ __launch_bounds__(256) void prep_small(
    const float* __restrict__ lz, const float* __restrict__ lw,
    const float* __restrict__ gamma, const float* __restrict__ delta,
    const float* __restrict__ pks, const float* __restrict__ Lp,
    float* __restrict__ consts, float* __restrict__ a_tab, float* __restrict__ b_tab,
    float* __restrict__ g_tab, float* __restrict__ d_tab, float* __restrict__ out)
{
  int n = blockIdx.x * blockDim.x + threadIdx.x;
  float Lv = softplus_ref(Lp[0]);
  if (n == 0) out[0] = 0.f;
  if (n < N1) {
    float z0 = lz[n*3], z1 = lz[n*3+1], z2 = lz[n*3+2];
    float m = fmaxf(z0, fmaxf(z1, z2));
    float e0 = expf(z0-m), e1 = expf(z1-m), e2 = expf(z2-m);
    float inv = 1.f/(e0+e1+e2);
    a_tab[0*N1+n] = e0*inv*Lv; a_tab[1*N1+n] = e1*inv*Lv; a_tab[2*N1+n] = e2*inv*Lv;
    float w0 = lw[n*3], w1 = lw[n*3+1], w2 = lw[n*3+2];
    m = fmaxf(w0, fmaxf(w1, w2));
    e0 = expf(w0-m); e1 = expf(w1-m); e2 = expf(w2-m);
    inv = 1.f/(e0+e1+e2);
    b_tab[0*N2+n] = e0*inv+EPSV; b_tab[1*N2+n] = e1*inv+EPSV; b_tab[2*N2+n] = e2*inv+EPSV;
    #pragma unroll
    for (int k = 0; k < 3; ++k) {
      g_tab[k*N1+n] = gamma[n*3+k];
      d_tab[k*N2+n] = delta[n*3+k];
    }
  }
  if (n < NLAYERS) {
    float p[KKC+1]; float m = -1e30f;
    for (int k = 0; k <= KKC; ++k) { p[k] = pks[n*(KKC+1)+k]; m = fmaxf(m, p[k]); }
    float s = 0.f;
    for (int k = 0; k <= KKC; ++k) { p[k] = expf(p[k]-m); s += p[k]; }
    float inv = 1.f/s;
    for (int k = 0; k <= KKC; ++k) consts[8 + n*(KKC+1) + k] = p[k]*inv;
    consts[n] = p[0]*inv + EPSV*(1.f - p[0]*inv);  // c = p0 + EPS*(1-p0)
  }
}

// ---------------- prep_rows: wave-per-row softmax (+pyramid for z) ----------------
// grid (N/4, NLAYERS, 2): z==0 -> z-mode (us -> zt, hierarchical kernel M), z==1 -> w (vs -> wt).
// Lane l holds 16 contiguous elems [l*16 .. l*16+15]. No LDS, no syncthreads.
__global__ __launch_bounds__(256) void prep_rows(
    const float* __restrict__ us, const float* __restrict__ vs,
    bf16_t* __restrict__ zt, bf16_t* __restrict__ wt, size_t lstride,
    const float* __restrict__ consts, int layer0)
{
  const int t = threadIdx.x, w = t >> 6, l = t & 63;
  const int n = blockIdx.x*4 + w;
  const int layer = layer0 + blockIdx.y;
  const int zmode = (blockIdx.z == 0);
  const float* src = (zmode ? us : vs) + ((size_t)layer*N1 + n)*DD + l*16;
  bf16_t* dst = (zmode ? zt : wt) + (size_t)blockIdx.y*lstride + (size_t)n*DD + l*16;

  float e[16];
  {
    const float4* s4 = (const float4*)src;
    float4 u0 = s4[0], u1 = s4[1], u2 = s4[2], u3 = s4[3];
    e[0]=u0.x; e[1]=u0.y; e[2]=u0.z; e[3]=u0.w;
    e[4]=u1.x; e[5]=u1.y; e[6]=u1.z; e[7]=u1.w;
    e[8]=u2.x; e[9]=u2.y; e[10]=u2.z; e[11]=u2.w;
    e[12]=u3.x; e[13]=u3.y; e[14]=u3.z; e[15]=u3.w;
  }
  float mx = e[0];
  #pragma unroll
  for (int i = 1; i < 16; ++i) mx = fmaxf(mx, e[i]);
  mx = wredmax(mx);
  float s = 0.f;
  #pragma unroll
  for (int i = 0; i < 16; ++i) { e[i] = __expf(e[i]-mx); s += e[i]; }
  s = wredsum(s);
  float inv = 1.f/s;
  #pragma unroll
  for (int i = 0; i < 16; ++i) e[i] *= inv;

  if (!zmode) {
    bf16x8 o0, o1;
    #pragma unroll
    for (int i = 0; i < 8; ++i) { o0[i] = (bf16_t)e[i]; o1[i] = (bf16_t)e[8+i]; }
    *(bf16x8*)dst = o0; *(bf16x8*)(dst+8) = o1;
    return;
  }
  // pyramid partial sums: levels 1-4 in-lane, 5-9 cross-lane
  float s1[8], s2[4], s3[2], s4v;
  #pragma unroll
  for (int i = 0; i < 8; ++i) s1[i] = e[2*i] + e[2*i+1];
  #pragma unroll
  for (int i = 0; i < 4; ++i) s2[i] = s1[2*i] + s1[2*i+1];
  s3[0] = s2[0]+s2[1]; s3[1] = s2[2]+s2[3];
  s4v = s3[0]+s3[1];
  float s5 = s4v + __shfl_xor(s4v, 1, 64);
  float s6 = s5  + __shfl_xor(s5, 2, 64);
  float s7 = s6  + __shfl_xor(s6, 4, 64);
  float s8 = s7  + __shfl_xor(s7, 8, 64);
  float s9 = s8  + __shfl_xor(s8, 16, 64);
  const float* pk = consts + 8 + layer*(KKC+1);
  const float base = pk[4]*s4v + pk[5]*s5 + pk[6]*s6 + pk[7]*s7 + pk[8]*s8 + pk[9]*s9;
  const float p1 = pk[1], p2 = pk[2], p3 = pk[3], p10 = pk[10];
  bf16x8 o0, o1;
  #pragma unroll
  for (int i = 0; i < 8; ++i) {
    o0[i] = (bf16_t)(p10*e[i]   + p1*s1[i>>1]     + p2*s2[i>>2]     + p3*s3[i>>3]     + base);
    o1[i] = (bf16_t)(p10*e[8+i] + p1*s1[(8+i)>>1] + p2*s2[(8+i)>>2] + p3*s3[1]        + base);
  }
  *(bf16x8*)dst = o0; *(bf16x8*)(dst+8) = o1;
}

// ---------------- 256x256 8-phase GEMM (K-loop identical to R6) + LDS-staged epilogue ----------------
__global__ __launch_bounds__(512, 2) void gemm_fused(
    const bf16_t* __restrict__ Az, size_t zls,
    const bf16_t* __restrict__ Bw, size_t wls,
    const float* __restrict__ a_tab, const float* __restrict__ b_tab,
    const float* __restrict__ g_tab, const float* __restrict__ d_tab,
    const float* __restrict__ consts, int layer0,
    bf16_t* __restrict__ inter, size_t ils, float* __restrict__ out)
{
  extern __shared__ char lds[];                // 2 x 64KB
  const int t = threadIdx.x;
  const int w = t >> 6, l = t & 63;
  const int wm = w >> 2, wn = w & 3;           // 2x4 wave grid; wave tile 128x64
  const int fr = l & 15, fq = l >> 4;

  // T1: bijective XCD swizzle (nblk % 8 == 0 in both call sites)
  const int nbx = gridDim.x, nby = gridDim.y;
  int lid = blockIdx.x + nbx*(blockIdx.y + nby*blockIdx.z);
  const int nblk = nbx*nby*gridDim.z;
  const int cpx = nblk >> 3;
  int nid = (lid & 7)*cpx + (lid >> 3);
  const int bz = nid / (nbx*nby);
  const int rem = nid % (nbx*nby);
  const int bi = rem % nbx, bj = rem / nbx;

  const int i0 = bi*256, j0 = bj*256;
  const int layer = layer0 + bz;
  Az += (size_t)bz*zls + (size_t)i0*DD;
  Bw += (size_t)bz*wls + (size_t)j0*DD;
  if (inter) inter += (size_t)bz*ils;

  f32x4 acc[8][4];
  f32x4 zero = {0.f, 0.f, 0.f, 0.f};
  #pragma unroll
  for (int m = 0; m < 8; ++m)
    #pragma unroll
    for (int nn = 0; nn < 4; ++nn) acc[m][nn] = zero;

  const int srow = w*8 + (l >> 3);
  const int sgs  = (l & 7) ^ (srow & 7);
  const size_t so0 = (size_t)srow*DD + (size_t)sgs*8;
  const size_t so1 = so0 + (size_t)64*DD;
  const int sx = fr & 7;
  const int aofs0 = wm*16384 + fr*128 + ((0+fq)^sx)*16;
  const int aofs1 = wm*16384 + fr*128 + ((4+fq)^sx)*16;
  const int bofs0 = 32768 + wn*8192 + fr*128 + ((0+fq)^sx)*16;
  const int bofs1 = 32768 + wn*8192 + fr*128 + ((4+fq)^sx)*16;

  bf16x8 ar[8], br[8];

#define STG(matptr, matofs, half, tile) do { \
    const bf16_t* _s = (matptr) + (size_t)(half)*128*DD + (size_t)(tile)*64; \
    char* _d = lds + ((tile)&1)*65536 + (matofs) + (half)*16384 + w*1024; \
    global_load_lds16(_s + so0, _d); \
    global_load_lds16(_s + so1, _d + 8192); \
  } while (0)
#define LDA(bufb, mq) do { \
    const char* _b = lds + (bufb); \
    _Pragma("unroll") for (int i = 0; i < 4; ++i) { \
      ar[i]   = *(const bf16x8*)(_b + aofs0 + ((mq)*4+i)*2048); \
      ar[4+i] = *(const bf16x8*)(_b + aofs1 + ((mq)*4+i)*2048); } \
  } while (0)
#define LDB(bufb, nq) do { \
    const char* _b = lds + (bufb); \
    _Pragma("unroll") for (int j = 0; j < 2; ++j) { \
      br[(nq)*2+j]   = *(const bf16x8*)(_b + bofs0 + ((nq)*2+j)*2048); \
      br[4+(nq)*2+j] = *(const bf16x8*)(_b + bofs1 + ((nq)*2+j)*2048); } \
  } while (0)
#define MM(mq, nq) do { \
    _Pragma("unroll") for (int k = 0; k < 2; ++k) \
    _Pragma("unroll") for (int i = 0; i < 4; ++i) \
    _Pragma("unroll") for (int j = 0; j < 2; ++j) \
      acc[(mq)*4+i][(nq)*2+j] = __builtin_amdgcn_mfma_f32_16x16x32_bf16( \
          ar[k*4+i], br[k*4+(nq)*2+j], acc[(mq)*4+i][(nq)*2+j], 0, 0, 0); \
  } while (0)
#define SYNC_MFMA(mq, nq) do { \
    asm volatile("s_barrier" ::: "memory"); \
    asm volatile("s_waitcnt lgkmcnt(0)" ::: "memory"); \
    __builtin_amdgcn_sched_barrier(0); \
    __builtin_amdgcn_s_setprio(1); \
    MM(mq, nq); \
    __builtin_amdgcn_s_setprio(0); \
  } while (0)
#define CLOSE() asm volatile("s_barrier" ::: "memory")

  STG(Az, 0, 0, 0); STG(Az, 0, 1, 0); STG(Bw, 32768, 0, 0); STG(Bw, 32768, 1, 0);
  STG(Az, 0, 0, 1); STG(Az, 0, 1, 1); STG(Bw, 32768, 0, 1); STG(Bw, 32768, 1, 1);
  asm volatile("s_waitcnt vmcnt(8)" ::: "memory");
  asm volatile("s_barrier" ::: "memory");

  for (int it = 0; it < 8; ++it) {
    const int k1 = 2*it + 1;
    const bool sE = (it >= 1);
    const bool sL = (it <= 6);

    LDA(0, 0); LDB(0, 0);
    if (sE) STG(Az, 0, 1, k1);
    asm volatile("s_waitcnt lgkmcnt(8)" ::: "memory");
    SYNC_MFMA(0, 0); CLOSE();
    LDB(0, 1);
    if (sE) STG(Bw, 32768, 0, k1);
    SYNC_MFMA(0, 1); CLOSE();
    LDA(0, 1);
    if (sE) STG(Bw, 32768, 1, k1);
    SYNC_MFMA(1, 0); CLOSE();
    if (sL) STG(Az, 0, 0, k1+1);
    SYNC_MFMA(1, 1);
    if (it < 7) asm volatile("s_waitcnt vmcnt(2)" ::: "memory");
    else        asm volatile("s_waitcnt vmcnt(0)" ::: "memory");
    CLOSE();

    LDA(65536, 0); LDB(65536, 0);
    if (sL) STG(Az, 0, 1, k1+1);
    asm volatile("s_waitcnt lgkmcnt(8)" ::: "memory");
    SYNC_MFMA(0, 0); CLOSE();
    LDB(65536, 1);
    if (sL) STG(Bw, 32768, 0, k1+1);
    SYNC_MFMA(0, 1); CLOSE();
    LDA(65536, 1);
    if (sL) STG(Bw, 32768, 1, k1+1);
    SYNC_MFMA(1, 0); CLOSE();
    if (sL) STG(Az, 0, 0, k1+2);
    SYNC_MFMA(1, 1);
    if (sL) asm volatile("s_waitcnt vmcnt(2)" ::: "memory");
    CLOSE();
  }
#undef STG
#undef LDA
#undef LDB
#undef MM
#undef SYNC_MFMA
#undef CLOSE

  // ---- epilogue: stage C (bf16, +cc) into LDS row-major 256x512B, then coalesced
  //      16B stores to inter + softplus-sum from the same chunks ----
  const float cc = consts[layer];
  {
    // byte addr = row*512 + col*2; row = wm*128+m*16+fq*4+r, col = wn*64+nn*16+fr
    char* cbase = lds + wm*65536 + fq*2048 + wn*128 + fr*2;
    #pragma unroll
    for (int m = 0; m < 8; ++m)
      #pragma unroll
      for (int nn = 0; nn < 4; ++nn)
        #pragma unroll
        for (int r = 0; r < 4; ++r)
          *(bf16_t*)(cbase + m*8192 + r*512 + nn*32) = (bf16_t)(acc[m][nn][r] + cc);
  }
  __syncthreads();

  const float* at = a_tab + layer*N1;
  const float* bt = b_tab + layer*N2;
  const float* gt = g_tab + layer*N1;
  const float* dt = d_tab + layer*N2;
  float lsum = 0.f;
  #pragma unroll 4
  for (int i = 0; i < 16; ++i) {
    const int id = t + i*512;            // 8192 chunks of 16B
    const int row = id >> 5, g = id & 31;
    bf16x8 v = *(const bf16x8*)(lds + row*512 + g*16);
    const int grow = i0 + row, gcol = j0 + g*8;
    if (inter) *(bf16x8*)(inter + (size_t)grow*N2 + gcol) = v;
    const float av = at[grow], gv = gt[grow];
    float4 b0 = *(const float4*)(bt + gcol), b1 = *(const float4*)(bt + gcol + 4);
    float4 d0 = *(const float4*)(dt + gcol), d1 = *(const float4*)(dt + gcol + 4);
    float bb[8] = {b0.x,b0.y,b0.z,b0.w,b1.x,b1.y,b1.z,b1.w};
    float dd[8] = {d0.x,d0.y,d0.z,d0.w,d1.x,d1.y,d1.z,d1.w};
    #pragma unroll
    for (int e2 = 0; e2 < 8; ++e2) {
      float x = av*bb[e2]*(float)v[e2] + gv + dd[e2];
      float sp = softplus_fast(x);
      lsum += (grow != gcol + e2) ? sp : 0.f;
    }
  }
  lsum = wredsum(lsum);
  __syncthreads();
  if (l == 0) ((float*)lds)[w] = lsum;
  __syncthreads();
  if (t == 0) {
    const float* r = (const float*)lds;
    float s = 0.f;
    #pragma unroll
    for (int i = 0; i < 8; ++i) s += r[i];
    atomicAdd(out, -s);   // ll -= z_pdist1
  }
}

// ---------------- sparse: gather from materialized inter (layer-batched) ----------------
__global__ __launch_bounds__(256) void sparse_gather(
    const int* __restrict__ is_, const int* __restrict__ js_,
    const bf16_t* __restrict__ inter, size_t ils,
    const float* __restrict__ a_tab, const float* __restrict__ b_tab,
    const float* __restrict__ g_tab, const float* __restrict__ d_tab,
    int layer0, int E, float* __restrict__ out)
{
  const int layer = layer0 + blockIdx.y;
  int e = blockIdx.x * blockDim.x + threadIdx.x;
  float v = 0.f;
  if (e < E) {
    int i = is_[(size_t)blockIdx.y*E + e], j = js_[(size_t)blockIdx.y*E + e];
    float dc = (float)inter[(size_t)blockIdx.y*ils + (size_t)i*N2 + j];
    v = a_tab[layer*N1+i] * b_tab[layer*N2+j] * dc + g_tab[layer*N1+i] + d_tab[layer*N2+j];
  }
  v = wredsum(v);
  __shared__ float red[4];
  int w = threadIdx.x >> 6, l = threadIdx.x & 63;
  if (l == 0) red[w] = v;
  __syncthreads();
  if (threadIdx.x == 0) atomicAdd(out, red[0] + red[1] + red[2] + red[3]);
}

// ---------------- fallback sparse: per-edge dot (ws too small for inter) ----------------
__global__ __launch_bounds__(256) void sparse_dot(
    const int* __restrict__ is_, const int* __restrict__ js_,
    const bf16_t* __restrict__ zt, const bf16_t* __restrict__ wt,
    const float* __restrict__ a_tab, const float* __restrict__ b_tab,
    const float* __restrict__ g_tab, const float* __restrict__ d_tab,
    const float* __restrict__ consts, int layer, float* __restrict__ out)
{
  const int t = threadIdx.x, w = t >> 6, l = t & 63;
  const float cc = consts[layer];
  float accv = 0.f;
  for (int q = 0; q < 8; ++q) {
    int e = (blockIdx.x*4 + w)*8 + q;
    int i = is_[e], j = js_[e];
    const bf16x8* zr = (const bf16x8*)(zt + (size_t)i*DD) + l*2;
    const bf16x8* wr = (const bf16x8*)(wt + (size_t)j*DD) + l*2;
    float dot = 0.f;
    #pragma unroll
    for (int x = 0; x < 2; ++x) {
      bf16x8 a = zr[x], b = wr[x];
      #pragma unroll
      for (int y = 0; y < 8; ++y) dot += (float)a[y] * (float)b[y];
    }
    dot = wredsum(dot);
    if (l == 0)
      accv += a_tab[layer*N1+i]*b_tab[layer*N2+j]*(dot+cc) + g_tab[layer*N1+i] + d_tab[layer*N2+j];
  }
  __shared__ float red[4];
  if (l == 0) red[w] = accv;
  __syncthreads();
  if (t == 0) atomicAdd(out, red[0] + red[1] + red[2] + red[3]);
}

extern "C" void kernel_launch(void* const* d_in, const int* in_sizes, int n_in,
                              void* d_out, int out_size, void* d_ws, size_t ws_size,
                              hipStream_t stream) {
  const float* us    = (const float*)d_in[0];
  const float* vs    = (const float*)d_in[1];
  const float* gamma = (const float*)d_in[2];
  const float* delta = (const float*)d_in[3];
  const float* lz    = (const float*)d_in[4];
  const float* lw    = (const float*)d_in[5];
  const float* pks   = (const float*)d_in[6];
  const float* Lp    = (const float*)d_in[7];
  const int*   sis   = (const int*)d_in[8];
  const int*   sjs   = (const int*)d_in[9];
  float* out = (float*)d_out;
  char*  ws  = (char*)d_ws;

  float*  consts = (float*)(ws + OFF_CONSTS);
  float*  a_tab  = (float*)(ws + OFF_A);
  float*  b_tab  = (float*)(ws + OFF_B);
  float*  g_tab  = (float*)(ws + OFF_G);
  float*  d_tab  = (float*)(ws + OFF_D);
  const int E = in_sizes[8] / NLAYERS;
  if (ws_size < WS_MIN) return;
  const size_t LDSB = 131072;

  prep_small<<<(N1+255)/256, 256, 0, stream>>>(lz, lw, gamma, delta, pks, Lp,
                                               consts, a_tab, b_tab, g_tab, d_tab, out);

  if (ws_size >= WS_BATCH) {
    bf16_t* zt    = (bf16_t*)(ws + OFF_ZT);
    bf16_t* wt    = (bf16_t*)(ws + OFF_WT_B);
    bf16_t* inter = (bf16_t*)(ws + OFF_IN_B);
    prep_rows<<<dim3(N1/4, NLAYERS, 2), 256, 0, stream>>>(us, vs, zt, wt, ZT_LSTRIDE, consts, 0);
    gemm_fused<<<dim3(16,16,NLAYERS), 512, LDSB, stream>>>(
        zt, ZT_LSTRIDE, wt, ZT_LSTRIDE, a_tab, b_tab, g_tab, d_tab,
        consts, 0, inter, IN_LSTRIDE, out);
    sparse_gather<<<dim3((E+255)/256, NLAYERS), 256, 0, stream>>>(
        sis, sjs, inter, IN_LSTRIDE, a_tab, b_tab, g_tab, d_tab, 0, E, out);
  } else {
    bf16_t* zt    = (bf16_t*)(ws + OFF_ZT);
    bf16_t* wt    = (bf16_t*)(ws + OFF_WT_S);
    bf16_t* inter = (bf16_t*)(ws + OFF_IN_S);
    const bool full = ws_size >= WS_FULL;
    for (int lay = 0; lay < NLAYERS; ++lay) {
      prep_rows<<<dim3(N1/4, 1, 2), 256, 0, stream>>>(us, vs, zt, wt, 0, consts, lay);
      gemm_fused<<<dim3(16,16,1), 512, LDSB, stream>>>(
          zt, 0, wt, 0, a_tab, b_tab, g_tab, d_tab, consts, lay,
          full ? inter : (bf16_t*)nullptr, 0, out);
      if (full) {
        sparse_gather<<<dim3((E+255)/256,1), 256, 0, stream>>>(
            sis + (size_t)lay*E, sjs + (size_t)lay*E, inter, 0,
            a_tab, b_tab, g_tab, d_tab, lay, E, out);
      } else {
        sparse_dot<<<E/32, 256, 0, stream>>>(
            sis + (size_t)lay*E, sjs + (size_t)lay*E, zt, wt,
            a_tab, b_tab, g_tab, d_tab, consts, lay, out);
      }
    }
  }
}